// Round 12
// baseline (195.254 us; speedup 1.0000x reference)
//
#include <hip/hip_runtime.h>

// Lorenz RK4, B=16384, NT=2000, dt=0.01. out[b*6003 + d*2001 + t].
//
// Round-12: cut the loop-carried dependency chain 13 -> 10 levels.
// Aux states (recomputed EXACTLY from x',y',z' each step -- zero drift):
//   d = y - x,  w = p1 - z,  q = p2*z
// Stage shortcuts (each k-stage = 2 dep levels instead of 3):
//   k1x = p0*d; k1y = fma(x,w,-y); k1z = fma(x,y,-q)        (k1 @ L1)
//   k{i+1}x = fma(h*p0, k_iy - k_ix, k1x)                   (exact algebra)
//   k{i+1}y = fma(ax, wa, -ay),  wa = fma(-h, k_iz, w)
//   k{i+1}z = fma(ax, ay, -qa),  qa = fma(h*p2, k_iz, q)
// Everything else frozen at the round-4 structure (256 x 192, TT=64,
// 1 compute + 2 writer waves, double-buffered LDS).

#define TROWS  2001
#define ROWS   64
#define LROWS  65
#define TT     64
#define NFULL  31
#define TAIL   16

#define FMA(a,b,c) __builtin_fmaf((a),(b),(c))

#define STEP() do {                                                          \
        float k1x = p0 * d;                                                  \
        float k1y = FMA(x, w, -y);                                           \
        float k1z = FMA(x, y, -q);                                           \
        float e1  = k1y - k1x;                                               \
        float ax  = FMA(h2, k1x, x);                                         \
        float ay  = FMA(h2, k1y, y);                                         \
        float wa  = FMA(nh2, k1z, w);                                        \
        float qa  = FMA(h2p2, k1z, q);                                       \
        float k2x = FMA(h2p0, e1, k1x);                                      \
        float k2y = FMA(ax, wa, -ay);                                        \
        float k2z = FMA(ax, ay, -qa);                                        \
        float e2  = k2y - k2x;                                               \
        float bx  = FMA(h2, k2x, x);                                         \
        float by  = FMA(h2, k2y, y);                                         \
        float wb  = FMA(nh2, k2z, w);                                        \
        float qb  = FMA(h2p2, k2z, q);                                       \
        float k3x = FMA(h2p0, e2, k1x);                                      \
        float k3y = FMA(bx, wb, -by);                                        \
        float k3z = FMA(bx, by, -qb);                                        \
        float e3  = k3y - k3x;                                               \
        float cx  = FMA(h1, k3x, x);                                         \
        float cy  = FMA(h1, k3y, y);                                         \
        float wc  = FMA(nh1, k3z, w);                                        \
        float qc  = FMA(h1p2, k3z, q);                                       \
        float k4x = FMA(h1p0, e3, k1x);                                      \
        float k4y = FMA(cx, wc, -cy);                                        \
        float k4z = FMA(cx, cy, -qc);                                        \
        float sx = FMA(2.0f, k2x, k1x); sx = FMA(2.0f, k3x, sx); sx += k4x;  \
        float sy = FMA(2.0f, k2y, k1y); sy = FMA(2.0f, k3y, sy); sy += k4y;  \
        float sz = FMA(2.0f, k2z, k1z); sz = FMA(2.0f, k3z, sz); sz += k4z;  \
        x = FMA(h6, sx, x);                                                  \
        y = FMA(h6, sy, y);                                                  \
        z = FMA(h6, sz, z);                                                  \
        d = y - x;                                                           \
        w = p1 - z;                                                          \
        q = p2 * z;                                                          \
    } while (0)

__global__ __launch_bounds__(192) void lorenz_rk4(
    const float* __restrict__ x0,
    const float* __restrict__ p,
    float* __restrict__ out)
{
#pragma clang fp contract(off)
    __shared__ float buf[2][3][TT][LROWS];   // 99.8 KB

    const int tid  = threadIdx.x;
    const int lane = tid & 63;
    const int b0   = blockIdx.x * ROWS;

    if (tid < 64) {
        // ================= compute wave =================
        const float p0 = p[0], p1 = p[1], p2 = p[2];
        const float h1 = 0.01f, h2 = 0.01f / 2.0f, h6 = 0.01f / 6.0f;
        const float nh1 = -h1, nh2 = -h2;
        const float h2p0 = h2 * p0, h1p0 = h1 * p0;
        const float h2p2 = h2 * p2, h1p2 = h1 * p2;
        const int b = b0 + lane;
        float x = x0[3*b + 0], y = x0[3*b + 1], z = x0[3*b + 2];
        float d = y - x, w = p1 - z, q = p2 * z;

        {   // t = 0 column
            size_t g = (size_t)b * (3 * TROWS);
            out[g] = x; out[g + TROWS] = y; out[g + 2*TROWS] = z;
        }

        for (int k = 0; k < NFULL; ++k) {
            float* bb = &buf[k & 1][0][0][0];
#pragma unroll 8
            for (int tl = 0; tl < TT; ++tl) {
                STEP();
                bb[              tl*LROWS + lane] = x;
                bb[  TT*LROWS  + tl*LROWS + lane] = y;
                bb[2*TT*LROWS  + tl*LROWS + lane] = z;
            }
            __syncthreads();                  // tile k ready
        }
#pragma unroll 16
        for (int tl = 0; tl < TAIL; ++tl) {   // tail tile -> buf 1
            STEP();
            buf[1][0][tl][lane] = x;
            buf[1][1][tl][lane] = y;
            buf[1][2][tl][lane] = z;
        }
        __syncthreads();                      // tail ready
    } else {
        // ================= writer waves =================
        const int w     = (tid >> 6) - 1;     // 0 or 1
        const int rbase = w * 32;             // rows [rbase, rbase+32)
        const int t     = lane;               // time within tile

        for (int k = 0; k < NFULL; ++k) {
            __syncthreads();                  // wait: tile k ready
            const float* bb = &buf[k & 1][0][0][0];
            size_t g = (size_t)(b0 + rbase) * (3 * TROWS) + 1 + (size_t)k * TT + t;
#pragma unroll 4
            for (int r = rbase; r < rbase + 32; ++r) {
                out[g]             = bb[              t*LROWS + r];
                out[g +     TROWS] = bb[  TT*LROWS  + t*LROWS + r];
                out[g + 2 * TROWS] = bb[2*TT*LROWS  + t*LROWS + r];
                g += (size_t)(3 * TROWS);
            }
        }
        __syncthreads();                      // wait: tail ready
        {
            const int tloc = lane & 15;
            int rloc = rbase + (lane >> 4);   // 4 rows per instruction
            size_t g = (size_t)(b0 + rloc) * (3 * TROWS) + 1 + (size_t)NFULL * TT + tloc;
#pragma unroll 4
            for (int i = 0; i < 8; ++i) {
                out[g]             = buf[1][0][tloc][rloc];
                out[g +     TROWS] = buf[1][1][tloc][rloc];
                out[g + 2 * TROWS] = buf[1][2][tloc][rloc];
                rloc += 4;
                g    += (size_t)4 * (3 * TROWS);
            }
        }
    }
}

extern "C" void kernel_launch(void* const* d_in, const int* in_sizes, int n_in,
                              void* d_out, int out_size, void* d_ws, size_t ws_size,
                              hipStream_t stream)
{
    const float* x0  = (const float*)d_in[0];
    const float* p   = (const float*)d_in[1];
    float*       out = (float*)d_out;

    const int B = in_sizes[0] / 3;        // 16384
    const int nblocks = B / ROWS;         // 256

    lorenz_rk4<<<nblocks, 192, 0, stream>>>(x0, p, out);
}